// Round 1
// baseline (11.354 us; speedup 1.0000x reference)
//
#include <hip/hip_runtime.h>

// CrossModalCenterLoss: loss = sum_b clip(||x_b - centers[labels_b]||^2, 1e-12, 1e12)/B
//                              + (C-1)*1e-12   (masked-out entries clipped up from 0)
// x: [4096, 512] f32, labels: [4096] int, centers: [10000, 512] f32 -> scalar f32.

#define BATCH 4096
#define FEAT 512
#define NCLASS 10000
#define ROWS_PER_BLOCK 4   // 4 waves/block, one row per wave
#define NBLOCKS (BATCH / ROWS_PER_BLOCK)   // 1024

__global__ __launch_bounds__(256) void cmcl_rowdist(
    const float* __restrict__ x,
    const int* __restrict__ labels,
    const float* __restrict__ centers,
    float* __restrict__ partial)
{
    const int wave = threadIdx.x >> 6;
    const int lane = threadIdx.x & 63;
    const int row  = blockIdx.x * ROWS_PER_BLOCK + wave;

    const float4* __restrict__ xr =
        reinterpret_cast<const float4*>(x + (size_t)row * FEAT);
    const int lbl = labels[row];
    const float4* __restrict__ cr =
        reinterpret_cast<const float4*>(centers + (size_t)lbl * FEAT);

    // 512 floats = 128 float4 per row; 64 lanes -> 2 float4/lane, coalesced.
    float acc = 0.0f;
#pragma unroll
    for (int k = 0; k < 2; ++k) {
        const float4 xv = xr[lane + k * 64];
        const float4 cv = cr[lane + k * 64];
        const float d0 = xv.x - cv.x;
        const float d1 = xv.y - cv.y;
        const float d2 = xv.z - cv.z;
        const float d3 = xv.w - cv.w;
        acc += d0 * d0 + d1 * d1 + d2 * d2 + d3 * d3;
    }

    // wave64 butterfly reduce
#pragma unroll
    for (int off = 32; off > 0; off >>= 1)
        acc += __shfl_down(acc, off, 64);

    __shared__ float ws[ROWS_PER_BLOCK];
    if (lane == 0)
        ws[wave] = fminf(fmaxf(acc, 1e-12f), 1e12f);  // reference clip on live entry
    __syncthreads();
    if (threadIdx.x == 0)
        partial[blockIdx.x] = ws[0] + ws[1] + ws[2] + ws[3];
}

__global__ __launch_bounds__(256) void cmcl_reduce(
    const float* __restrict__ partial,
    float* __restrict__ out)
{
    const int tid = threadIdx.x;
    float acc = 0.0f;
#pragma unroll
    for (int k = 0; k < NBLOCKS / 256; ++k)
        acc += partial[tid + k * 256];

#pragma unroll
    for (int off = 32; off > 0; off >>= 1)
        acc += __shfl_down(acc, off, 64);

    __shared__ float ws[4];
    if ((tid & 63) == 0) ws[tid >> 6] = acc;
    __syncthreads();
    if (tid == 0) {
        const float masked_term = (float)(NCLASS - 1) * 1e-12f;  // (C-1)*1e-12
        out[0] = (ws[0] + ws[1] + ws[2] + ws[3]) / (float)BATCH + masked_term;
    }
}

extern "C" void kernel_launch(void* const* d_in, const int* in_sizes, int n_in,
                              void* d_out, int out_size, void* d_ws, size_t ws_size,
                              hipStream_t stream) {
    const float* x       = (const float*)d_in[0];
    const int*   labels  = (const int*)d_in[1];
    const float* centers = (const float*)d_in[2];
    float* out = (float*)d_out;
    float* partial = (float*)d_ws;  // 1024 floats = 4 KB scratch

    cmcl_rowdist<<<NBLOCKS, 256, 0, stream>>>(x, labels, centers, partial);
    cmcl_reduce<<<1, 256, 0, stream>>>(partial, out);
}